// Round 2
// baseline (41.382 us; speedup 1.0000x reference)
//
#include <hip/hip_runtime.h>
#include <hip/hip_bf16.h>

#define BATCH 16384
#define HIST 50
#define WAVES_PER_BLOCK 4     // 256 threads = 4 waves; one wave per batch element

// out[b] = sigmoid( sum_l z_l * w_l + u_e . y_e ),  z = softmax(w),
// w_l = item_emb[X[b,l]] . item_emb[y[b]]   (BETA=ALPHA=1)
//
// Layout: one 64-lane wave per batch element. Lane l owns history item l
// (lanes 50..63 masked out with w=-inf). y-row / u-row are wave-uniform ->
// scalar loads. Dot products are lane-private (no shuffles); softmax is two
// 6-step wave butterfly reductions.
__global__ __launch_bounds__(256, 4) void RUM_72980084294375_kernel(
    const int* __restrict__ u, const int* __restrict__ X, const int* __restrict__ y,
    const float* __restrict__ item_emb, const float* __restrict__ user_emb,
    float* __restrict__ out)
{
    const int lane = threadIdx.x & 63;
    const int bw   = blockIdx.x * WAVES_PER_BLOCK + (threadIdx.x >> 6);
    const int b    = __builtin_amdgcn_readfirstlane(bw);   // wave-uniform -> SGPR

    const float4* item4 = reinterpret_cast<const float4*>(item_emb);
    const float4* user4 = reinterpret_cast<const float4*>(user_emb);

    const int yi = y[b];                 // uniform scalar loads
    const int ui = u[b];
    const float4* __restrict__ yrow = item4 + (size_t)yi * 16;
    const float4* __restrict__ urow = user4 + (size_t)ui * 16;

    int idx = 0;                          // padding row (all zeros) for idle lanes
    if (lane < HIST) idx = X[b * HIST + lane];   // coalesced 50-int load
    const float4* __restrict__ xrow = item4 + (size_t)idx * 16;

    float w  = 0.0f;   // lane-private dot(x_l, y)
    float uy = 0.0f;   // wave-uniform dot(u, y), computed redundantly per lane
    #pragma unroll
    for (int e = 0; e < 16; ++e) {
        const float4 yv = yrow[e];
        const float4 xv = xrow[e];
        const float4 uv = urow[e];
        w  += xv.x * yv.x + xv.y * yv.y + xv.z * yv.z + xv.w * yv.w;
        uy += uv.x * yv.x + uv.y * yv.y + uv.z * yv.z + uv.w * yv.w;
    }

    if (lane >= HIST) w = -1e30f;

    // max over wave
    float mx = w;
    #pragma unroll
    for (int m = 1; m < 64; m <<= 1) mx = fmaxf(mx, __shfl_xor(mx, m, 64));

    const float e  = (lane < HIST) ? __expf(w - mx) : 0.0f;
    float s = e;            // sum of exp
    float t = e * w;        // sum of w * exp (e==0 on idle lanes)
    #pragma unroll
    for (int m = 1; m < 64; m <<= 1) {
        s += __shfl_xor(s, m, 64);
        t += __shfl_xor(t, m, 64);
    }

    if (lane == 0) {
        const float logit = t / s + uy;
        out[b] = 1.0f / (1.0f + __expf(-logit));
    }
}

extern "C" void kernel_launch(void* const* d_in, const int* in_sizes, int n_in,
                              void* d_out, int out_size, void* d_ws, size_t ws_size,
                              hipStream_t stream) {
    const int*   u        = (const int*)d_in[0];
    const int*   X        = (const int*)d_in[1];
    const int*   y        = (const int*)d_in[2];
    const float* item_emb = (const float*)d_in[3];
    const float* user_emb = (const float*)d_in[4];
    float*       out      = (float*)d_out;

    const int blocks = BATCH / WAVES_PER_BLOCK;  // 4096 blocks x 256 threads
    RUM_72980084294375_kernel<<<blocks, 256, 0, stream>>>(
        u, X, y, item_emb, user_emb, out);
}

// Round 3
// 33.566 us; speedup vs baseline: 1.2329x; 1.2329x over previous
//
#include <hip/hip_runtime.h>
#include <hip/hip_bf16.h>

#define BATCH 16384
#define HIST  50
#define GPB   16   // 16 batch elements per 256-thread block; 16 lanes each

// DPP row_ror move (16-lane row scope), pure VALU — keeps reductions off the
// LDS pipe. row_ror:n => dst lane i gets src lane (i+n)%16 within its row.
template<int CTRL>
__device__ __forceinline__ float dpp_mov(float x) {
    return __builtin_bit_cast(float,
        __builtin_amdgcn_update_dpp(0, __builtin_bit_cast(int, x),
                                    CTRL, 0xF, 0xF, true));
}
__device__ __forceinline__ float red16_add(float x) {
    x += dpp_mov<0x128>(x);   // row_ror:8
    x += dpp_mov<0x124>(x);   // row_ror:4
    x += dpp_mov<0x122>(x);   // row_ror:2
    x += dpp_mov<0x121>(x);   // row_ror:1
    return x;                 // all 16 lanes hold the full sum
}
__device__ __forceinline__ float red16_max(float x) {
    x = fmaxf(x, dpp_mov<0x128>(x));
    x = fmaxf(x, dpp_mov<0x124>(x));
    x = fmaxf(x, dpp_mov<0x122>(x));
    x = fmaxf(x, dpp_mov<0x121>(x));
    return x;
}

// out[b] = sigmoid( sum_l z_l*w_l + u_e.y_e ), z = softmax(w),
// w_l = item_emb[X[b,l]] . item_emb[y[b]]   (BETA=ALPHA=1)
__global__ __launch_bounds__(256, 4) void RUM_72980084294375_kernel(
    const int* __restrict__ u, const int* __restrict__ X, const int* __restrict__ y,
    const float* __restrict__ item_emb, const float* __restrict__ user_emb,
    float* __restrict__ out)
{
    __shared__ int sX[GPB * HIST];

    const int tid = threadIdx.x;
    const int b0  = blockIdx.x * GPB;

    // coalesced staging of this block's 16x50 indices
    for (int i = tid; i < GPB * HIST; i += 256)
        sX[i] = X[b0 * HIST + i];
    __syncthreads();

    const int g    = tid >> 4;
    const int lane = tid & 15;
    const int b    = b0 + g;

    const float4* item4 = reinterpret_cast<const float4*>(item_emb);
    const float4* user4 = reinterpret_cast<const float4*>(user_emb);

    const int yi = y[b];
    const int ui = u[b];
    const float4 y4 = item4[(size_t)yi * 16 + lane];   // coalesced 256B/group
    const float4 u4 = user4[(size_t)ui * 16 + lane];

    const float uy = red16_add(u4.x*y4.x + u4.y*y4.y + u4.z*y4.z + u4.w*y4.w);

    const int* gX = sX + g * HIST;

    // logits, 50 fully independent iterations; lane j%16 keeps w[j] in slot j/16
    float wv[4] = {-1e30f, -1e30f, -1e30f, -1e30f};
    #pragma unroll
    for (int j = 0; j < HIST; ++j) {
        const int idx = gX[j];                          // LDS broadcast per group
        const float4 xv = item4[(size_t)idx * 16 + lane];
        const float w = red16_add(xv.x*y4.x + xv.y*y4.y + xv.z*y4.z + xv.w*y4.w);
        if ((j & 15) == lane) wv[j >> 4] = w;           // compile-time slot index
    }

    // flat two-phase softmax-weighted mean of w
    float m = fmaxf(fmaxf(wv[0], wv[1]), fmaxf(wv[2], wv[3]));
    m = red16_max(m);

    float s = 0.0f, t = 0.0f;
    #pragma unroll
    for (int c = 0; c < 4; ++c) {
        const float e = __expf(wv[c] - m);              // pads: exp(-inf) = 0
        s += e;
        t += e * wv[c];
    }
    s = red16_add(s);
    t = red16_add(t);

    if (lane == 0) {
        const float logit = t / s + uy;
        out[b] = 1.0f / (1.0f + __expf(-logit));
    }
}

extern "C" void kernel_launch(void* const* d_in, const int* in_sizes, int n_in,
                              void* d_out, int out_size, void* d_ws, size_t ws_size,
                              hipStream_t stream) {
    const int*   u        = (const int*)d_in[0];
    const int*   X        = (const int*)d_in[1];
    const int*   y        = (const int*)d_in[2];
    const float* item_emb = (const float*)d_in[3];
    const float* user_emb = (const float*)d_in[4];
    float*       out      = (float*)d_out;

    const int blocks = BATCH / GPB;   // 1024
    RUM_72980084294375_kernel<<<blocks, 256, 0, stream>>>(
        u, X, y, item_emb, user_emb, out);
}